// Round 1
// 378.098 us; speedup vs baseline: 1.0174x; 1.0174x over previous
//
#include <hip/hip_runtime.h>
#include <stdint.h>

// ---------------------------------------------------------------------------
// MultiHeadAttnCoupling: B=4 N=128 -> BN=512 rows
//   Q = z(512x256) @ Wq(256x32768) + bq
//   K = x(512x512) @ Wk(512x32768) + bk ; V likewise
//   per (bn, h in 0..7): S = Q64x64 K^T /8 ; P=softmax(S); O = P V
//   out = O(512x32768) @ Wo(32768x512) + bo   (fp32 out)
//
// v2: transpose kernels ELIMINATED. Both GEMMs read the fp32 weights
// directly in column mode (lane-per-n dword loads: 256B coalesced per
// instruction; 8 k's per thread), convert in-register with
// v_cvt_pk_bf16_f32 and ds_write_b128 the transposed fragment row into the
// same XOR-swizzled LDS layout FRAG consumes. An XCD-aware block remap
// puts the m-blocks that share a weight n-panel on ONE XCD, 8 dispatch
// slots apart, so panel re-reads hit that XCD's L2 instead of HBM.
//
// ws layout (bytes): Qb@0  Kb@32M  Vb@64M  Ob@96M  xb@128M  zb@+512K
// (~129MB total; d_out no longer used as scratch)
// ---------------------------------------------------------------------------

typedef __attribute__((ext_vector_type(8))) short short8;
typedef __attribute__((ext_vector_type(4))) float floatx4;

__device__ __forceinline__ unsigned short f2bf(float f) {
  union { float f; unsigned int u; } v; v.f = f;
  unsigned int u = v.u + 0x7FFFu + ((v.u >> 16) & 1u);   // round-to-nearest-even
  return (unsigned short)(u >> 16);
}

// pack two fp32 -> two bf16 in one u32 (lo = first elem), RNE.
__device__ __forceinline__ unsigned int cvt_pk_bf16(float lo, float hi) {
  unsigned int r;
  asm("v_cvt_pk_bf16_f32 %0, %1, %2" : "=v"(r) : "v"(lo), "v"(hi));
  return r;
}

#define MFMA16(a, b, c) __builtin_amdgcn_mfma_f32_16x16x32_bf16((a), (b), (c), 0, 0, 0)

// Stage a 128-row x 64-k bf16 tile into LDS via global_load_lds (16B/lane).
// XOR swizzle: logical k-chunk c (16B granule) of row r stored at slot c^(r&7).
#define STAGE_TILE(SRC, LD, LDSARR)                                            \
  do {                                                                         \
    _Pragma("unroll") for (int i_ = 0; i_ < 4; ++i_) {                         \
      int e_ = tid + (i_ << 8);                                                \
      int r_ = e_ >> 3;                                                        \
      int c_ = (e_ & 7) ^ (r_ & 7);                                            \
      __builtin_amdgcn_global_load_lds(                                        \
          (const __attribute__((address_space(1))) unsigned int*)((SRC) +      \
              (size_t)r_ * (LD) + (c_ << 3)),                                  \
          (__attribute__((address_space(3))) unsigned int*)(&(LDSARR)[e_ << 3]),\
          16, 0, 0);                                                           \
    }                                                                          \
  } while (0)

// Fragment read: row in [0,128), KS in {0,1}; logical chunk = KS*4+quad,
// stored at (KS*4+quad)^(row&7). Element offset = row*64 + chunk*8.
#define FRAG(LDSARR, ROW, KS)                                                  \
  (*(const short8*)(&(LDSARR)[(((ROW) << 6)) +                                 \
      ((((((KS) << 2) + quad)) ^ ((ROW) & 7)) << 3)]))

// ---------------------------------------------------------------------------
// B-staging straight from fp32 W[k][n] (row stride LDW floats):
// thread owns (n, k-octet): 8 dword loads (each instruction = 64 consecutive
// n = 256B coalesced), cvt_pk -> 4 u32, one ds_write_b128 into the swizzled
// BT[n][k] tile. The k-part of the address is wave-uniform (SGPR base).
// Covers 128 n x 64 k per call.
// ---------------------------------------------------------------------------
template <int LDW>
__device__ __forceinline__ void stage_b_f32(const float* __restrict__ Wp,
                                            unsigned short* Bs, int tid) {
  const int n = tid & 127;                                   // lane-contiguous
  const int octb = __builtin_amdgcn_readfirstlane(tid >> 7); // wave-uniform
#pragma unroll
  for (int g = 0; g < 4; ++g) {
    const int oct = octb + 2 * g;                            // k-octet, uniform
    const float* src = Wp + (size_t)(oct << 3) * LDW + n;
    float f[8];
#pragma unroll
    for (int j = 0; j < 8; ++j) f[j] = src[(size_t)j * LDW];
    uint4 p;
    p.x = cvt_pk_bf16(f[0], f[1]);
    p.y = cvt_pk_bf16(f[2], f[3]);
    p.z = cvt_pk_bf16(f[4], f[5]);
    p.w = cvt_pk_bf16(f[6], f[7]);
    *(uint4*)(&Bs[(n << 6) + ((oct ^ (n & 7)) << 3)]) = p;
  }
}

// ---------------- tiny streaming convert: x,z fp32 -> bf16 -----------------
__global__ __launch_bounds__(256) void convert_xz(const float* __restrict__ x,
                                                  const float* __restrict__ z,
                                                  unsigned short* __restrict__ xb,
                                                  unsigned short* __restrict__ zb) {
  int idx = (blockIdx.x * 256 + threadIdx.x) * 8;   // 192 blocks: 393216 elems
  const float* src;
  unsigned short* dst;
  if (idx < 262144) { src = x + idx; dst = xb + idx; }
  else              { src = z + (idx - 262144); dst = zb + (idx - 262144); }
  float4 f0 = *(const float4*)src;
  float4 f1 = *(const float4*)(src + 4);
  uint4 p;
  p.x = f2bf(f0.x) | ((unsigned)f2bf(f0.y) << 16);
  p.y = f2bf(f0.z) | ((unsigned)f2bf(f0.w) << 16);
  p.z = f2bf(f1.x) | ((unsigned)f2bf(f1.y) << 16);
  p.w = f2bf(f1.z) | ((unsigned)f2bf(f1.w) << 16);
  *(uint4*)dst = p;
}

// ---------------- fused QKV gemm: C_bf16 = A_bf16 * W_f32 + bias -----------
// grid (1024, 1, 3). Remap: xcd=id&7, j=id>>3; m=j&3; n-panel=xcd*32+(j>>2).
// The 4 m-blocks of a panel are ids {xcd+8*(4p+m)} -> same XCD, concurrent,
// so the fp32 weight panel is fetched from HBM once and L2-hit 3 times.
__global__ __launch_bounds__(256, 2) void gemm_qkv(const unsigned short* __restrict__ xb,
                                                   const unsigned short* __restrict__ zb,
                                                   const float* __restrict__ Wq,
                                                   const float* __restrict__ Wk,
                                                   const float* __restrict__ Wv,
                                                   const float* __restrict__ bq,
                                                   const float* __restrict__ bk,
                                                   const float* __restrict__ bv,
                                                   unsigned short* __restrict__ Qb,
                                                   unsigned short* __restrict__ Kb,
                                                   unsigned short* __restrict__ Vb) {
  __shared__ __align__(16) unsigned short As[128 * 64];
  __shared__ __align__(16) unsigned short Bs[128 * 64];
  const int tid = threadIdx.x;
  const int zsel = blockIdx.z;
  const unsigned short* A;
  const float* W;
  const float* bias;
  unsigned short* C;
  int Ka;
  if (zsel == 0)      { A = zb; W = Wq; bias = bq; C = Qb; Ka = 256; }
  else if (zsel == 1) { A = xb; W = Wk; bias = bk; C = Kb; Ka = 512; }
  else                { A = xb; W = Wv; bias = bv; C = Vb; Ka = 512; }
  const int id = blockIdx.x;
  const int xcd = id & 7, bj = id >> 3;
  const int m0 = (bj & 3) << 7;
  const int n0 = ((xcd << 5) | (bj >> 2)) << 7;
  const int lane = tid & 63, wid = tid >> 6;
  const int quad = lane >> 4, l15 = lane & 15;
  const int wm = wid >> 1, wn = wid & 1;
  floatx4 acc[4][4] = {};
  for (int k0 = 0; k0 < Ka; k0 += 64) {
    STAGE_TILE(A + (size_t)m0 * Ka + k0, Ka, As);
    stage_b_f32<32768>(W + (size_t)k0 * 32768 + n0, Bs, tid);
    __syncthreads();
#pragma unroll
    for (int ks = 0; ks < 2; ++ks) {
      short8 aF[4], bF[4];
#pragma unroll
      for (int mi = 0; mi < 4; ++mi) aF[mi] = FRAG(As, wm * 64 + mi * 16 + l15, ks);
#pragma unroll
      for (int ni = 0; ni < 4; ++ni) bF[ni] = FRAG(Bs, wn * 64 + ni * 16 + l15, ks);
#pragma unroll
      for (int mi = 0; mi < 4; ++mi)
#pragma unroll
        for (int ni = 0; ni < 4; ++ni)
          acc[mi][ni] = MFMA16(aF[mi], bF[ni], acc[mi][ni]);
    }
    __syncthreads();
  }
#pragma unroll
  for (int ni = 0; ni < 4; ++ni) {
    int col = n0 + wn * 64 + ni * 16 + l15;
    float bv2 = bias[col];
#pragma unroll
    for (int mi = 0; mi < 4; ++mi) {
      int row = m0 + wm * 64 + mi * 16 + (quad << 2);
#pragma unroll
      for (int r = 0; r < 4; ++r)
        C[(size_t)(row + r) * 32768 + col] = f2bf(acc[mi][ni][r] + bv2);
    }
  }
}

// ---------------- attention: one block per (bn, h), 64x64 tiles ------------
__global__ __launch_bounds__(256) void attn64(const unsigned short* __restrict__ Qb,
                                              const unsigned short* __restrict__ Kb,
                                              const unsigned short* __restrict__ Vb,
                                              unsigned short* __restrict__ Ob) {
  __shared__ __align__(16) unsigned short Qs[64 * 72];
  __shared__ __align__(16) unsigned short Ks[64 * 72];
  __shared__ __align__(16) unsigned short VT[64 * 72];
  __shared__ __align__(16) unsigned short Ps[64 * 72];
  const int tid = threadIdx.x;
  const int bn = blockIdx.x >> 3, h = blockIdx.x & 7;
  const size_t base = (size_t)bn * 32768 + (size_t)h * 4096;
  const unsigned short* q = Qb + base;
  const unsigned short* k = Kb + base;
  const unsigned short* v = Vb + base;
#pragma unroll
  for (int i = 0; i < 2; ++i) {
    int e = tid + (i << 8);
    int r = e >> 3, dblk = e & 7;
    *(uint4*)(&Qs[r * 72 + dblk * 8]) = *(const uint4*)(q + r * 64 + dblk * 8);
    *(uint4*)(&Ks[r * 72 + dblk * 8]) = *(const uint4*)(k + r * 64 + dblk * 8);
    uint4 vv = *(const uint4*)(v + r * 64 + dblk * 8);
    const unsigned short* pv = (const unsigned short*)&vv;
#pragma unroll
    for (int j = 0; j < 8; ++j)
      VT[(dblk * 8 + j) * 72 + r] = pv[j];
  }
  __syncthreads();
  const int lane = tid & 63, wid = tid >> 6;
  const int quad = lane >> 4, l15 = lane & 15;
  const int qs = wid << 4;
  short8 aq0 = *(const short8*)(&Qs[(qs + l15) * 72 + quad * 8]);
  short8 aq1 = *(const short8*)(&Qs[(qs + l15) * 72 + 32 + quad * 8]);
  floatx4 s[4] = {};
#pragma unroll
  for (int ni = 0; ni < 4; ++ni) {
    short8 b0 = *(const short8*)(&Ks[(ni * 16 + l15) * 72 + quad * 8]);
    short8 b1 = *(const short8*)(&Ks[(ni * 16 + l15) * 72 + 32 + quad * 8]);
    s[ni] = MFMA16(aq0, b0, s[ni]);
    s[ni] = MFMA16(aq1, b1, s[ni]);
  }
#pragma unroll
  for (int r = 0; r < 4; ++r) {
    float e0 = s[0][r] * 0.125f, e1 = s[1][r] * 0.125f;
    float e2 = s[2][r] * 0.125f, e3 = s[3][r] * 0.125f;
    float m = fmaxf(fmaxf(e0, e1), fmaxf(e2, e3));
    m = fmaxf(m, __shfl_xor(m, 1));
    m = fmaxf(m, __shfl_xor(m, 2));
    m = fmaxf(m, __shfl_xor(m, 4));
    m = fmaxf(m, __shfl_xor(m, 8));
    float x0 = __expf(e0 - m), x1 = __expf(e1 - m);
    float x2 = __expf(e2 - m), x3 = __expf(e3 - m);
    float t = x0 + x1 + x2 + x3;
    t += __shfl_xor(t, 1); t += __shfl_xor(t, 2);
    t += __shfl_xor(t, 4); t += __shfl_xor(t, 8);
    float inv = __builtin_amdgcn_rcpf(t);
    int row = qs + (quad << 2) + r;
    Ps[row * 72 +      l15] = f2bf(x0 * inv);
    Ps[row * 72 + 16 + l15] = f2bf(x1 * inv);
    Ps[row * 72 + 32 + l15] = f2bf(x2 * inv);
    Ps[row * 72 + 48 + l15] = f2bf(x3 * inv);
  }
  __syncthreads();
  short8 ap0 = *(const short8*)(&Ps[(qs + l15) * 72 + quad * 8]);
  short8 ap1 = *(const short8*)(&Ps[(qs + l15) * 72 + 32 + quad * 8]);
  floatx4 o[4] = {};
#pragma unroll
  for (int ni = 0; ni < 4; ++ni) {
    short8 b0 = *(const short8*)(&VT[(ni * 16 + l15) * 72 + quad * 8]);
    short8 b1 = *(const short8*)(&VT[(ni * 16 + l15) * 72 + 32 + quad * 8]);
    o[ni] = MFMA16(ap0, b0, o[ni]);
    o[ni] = MFMA16(ap1, b1, o[ni]);
  }
  unsigned short* outp = Ob + base;
#pragma unroll
  for (int ni = 0; ni < 4; ++ni)
#pragma unroll
    for (int r = 0; r < 4; ++r)
      outp[(qs + (quad << 2) + r) * 64 + ni * 16 + l15] = f2bf(o[ni][r]);
}

// ---------------- out gemm: C_f32[512][512] += Ob * Wo_f32 + bo ------------
// grid (512). Remap: xcd=id&7, j=id>>3 (0..63): m=j&3, q=j>>2 (0..15):
// n=q&3, ks=xcd*4+(q>>2). The 4 m-blocks sharing a (n, ks) Wo chunk sit on
// one XCD, 8 dispatch slots apart. Split-K 32 via atomicAdd (C pre-zeroed).
__global__ __launch_bounds__(256, 2) void gemm_out(const unsigned short* __restrict__ A,
                                                   const float* __restrict__ Wo,
                                                   const float* __restrict__ bias,
                                                   float* __restrict__ C) {
  __shared__ __align__(16) unsigned short As[128 * 64];
  __shared__ __align__(16) unsigned short Bs[128 * 64];
  const int tid = threadIdx.x;
  const int id = blockIdx.x;
  const int xcd = id & 7, bj = id >> 3;
  const int m0 = (bj & 3) << 7;
  const int q = bj >> 2;
  const int n0 = (q & 3) << 7;
  const int ks = (xcd << 2) | (q >> 2);
  const int kbase = ks << 10;
  const int lane = tid & 63, wid = tid >> 6;
  const int quad = lane >> 4, l15 = lane & 15;
  const int wm = wid >> 1, wn = wid & 1;
  floatx4 acc[4][4] = {};
  for (int k0 = kbase; k0 < kbase + 1024; k0 += 64) {
    STAGE_TILE(A + (size_t)m0 * 32768 + k0, 32768, As);
    stage_b_f32<512>(Wo + (size_t)k0 * 512 + n0, Bs, tid);
    __syncthreads();
#pragma unroll
    for (int kss = 0; kss < 2; ++kss) {
      short8 aF[4], bF[4];
#pragma unroll
      for (int mi = 0; mi < 4; ++mi) aF[mi] = FRAG(As, wm * 64 + mi * 16 + l15, kss);
#pragma unroll
      for (int ni = 0; ni < 4; ++ni) bF[ni] = FRAG(Bs, wn * 64 + ni * 16 + l15, kss);
#pragma unroll
      for (int mi = 0; mi < 4; ++mi)
#pragma unroll
        for (int ni = 0; ni < 4; ++ni)
          acc[mi][ni] = MFMA16(aF[mi], bF[ni], acc[mi][ni]);
    }
    __syncthreads();
  }
#pragma unroll
  for (int ni = 0; ni < 4; ++ni) {
    int col = n0 + wn * 64 + ni * 16 + l15;
    float bv0 = (ks == 0) ? bias[col] : 0.0f;
#pragma unroll
    for (int mi = 0; mi < 4; ++mi) {
      int row = m0 + wm * 64 + mi * 16 + (quad << 2);
#pragma unroll
      for (int r = 0; r < 4; ++r)
        atomicAdd(&C[(size_t)(row + r) * 512 + col], acc[mi][ni][r] + bv0);
    }
  }
}

extern "C" void kernel_launch(void* const* d_in, const int* in_sizes, int n_in,
                              void* d_out, int out_size, void* d_ws, size_t ws_size,
                              hipStream_t stream) {
  const float* x  = (const float*)d_in[0];
  const float* z  = (const float*)d_in[1];
  const float* Wq = (const float*)d_in[2];
  const float* bq = (const float*)d_in[3];
  const float* Wk = (const float*)d_in[4];
  const float* bk = (const float*)d_in[5];
  const float* Wv = (const float*)d_in[6];
  const float* bv = (const float*)d_in[7];
  const float* Wo = (const float*)d_in[8];
  const float* bo = (const float*)d_in[9];
  float* out = (float*)d_out;
  char* ws = (char*)d_ws;

  unsigned short* Qb = (unsigned short*)(ws + 0);
  unsigned short* Kb = (unsigned short*)(ws + 33554432);
  unsigned short* Vb = (unsigned short*)(ws + 67108864);
  unsigned short* Ob = (unsigned short*)(ws + 100663296);
  unsigned short* xb = (unsigned short*)(ws + 134217728);
  unsigned short* zb = (unsigned short*)(ws + 134217728 + 524288);

  convert_xz<<<dim3(192), 256, 0, stream>>>(x, z, xb, zb);

  gemm_qkv<<<dim3(1024, 1, 3), 256, 0, stream>>>(xb, zb, Wq, Wk, Wv,
                                                 bq, bk, bv, Qb, Kb, Vb);

  attn64<<<dim3(4096), 256, 0, stream>>>(Qb, Kb, Vb, Ob);

  hipMemsetAsync(d_out, 0, (size_t)out_size * sizeof(float), stream);
  gemm_out<<<dim3(512), 256, 0, stream>>>(Ob, Wo, bo, out);
}

// Round 3
// 350.274 us; speedup vs baseline: 1.0983x; 1.0794x over previous
//
#include <hip/hip_runtime.h>
#include <stdint.h>

// ---------------------------------------------------------------------------
// MultiHeadAttnCoupling: B=4 N=128 -> BN=512 rows
//   Q = z(512x256) @ Wq(256x32768) + bq
//   K = x(512x512) @ Wk(512x32768) + bk ; V likewise
//   per (bn, h in 0..7): S = Q64x64 K^T /8 ; P=softmax(S); O = P V
//   out = O(512x32768) @ Wo(32768x512) + bo   (fp32 out)
//
// v3 (resubmit; round-2 bench was an infra failure, no kernel evidence):
// fp32-weight column staging is SOFTWARE-PIPELINED: the 32 strided dword
// loads for K-step t+1 are issued into 32 distinct registers right after
// the barrier that publishes step t, and consumed (cvt_pk + swizzled
// ds_write_b128) only at the top of iteration t+1 -- they remain in flight
// across the whole MFMA phase. LDS tiles are double-buffered (64 KB,
// 2 blocks/CU), one barrier per K-step. gemm_out's atomics are replaced by
// fp32 partial tiles + a reduce kernel.
//
// ws layout (bytes):
//   Qb@0 (32M) Kb@32M Vb@64M Ob@96M  xb@128M(512K) zb@+512K(256K)
//   Cp@129M (32 partial C tiles, 32MB)  -> total 161MB
// ---------------------------------------------------------------------------

typedef __attribute__((ext_vector_type(8))) short short8;
typedef __attribute__((ext_vector_type(4))) float floatx4;

__device__ __forceinline__ unsigned short f2bf(float f) {
  union { float f; unsigned int u; } v; v.f = f;
  unsigned int u = v.u + 0x7FFFu + ((v.u >> 16) & 1u);   // round-to-nearest-even
  return (unsigned short)(u >> 16);
}

// pack two fp32 -> two bf16 in one u32 (lo = first elem), RNE.
__device__ __forceinline__ unsigned int cvt_pk_bf16(float lo, float hi) {
  unsigned int r;
  asm("v_cvt_pk_bf16_f32 %0, %1, %2" : "=v"(r) : "v"(lo), "v"(hi));
  return r;
}

#define MFMA16(a, b, c) __builtin_amdgcn_mfma_f32_16x16x32_bf16((a), (b), (c), 0, 0, 0)

// Stage a 128-row x 64-k bf16 tile into LDS via global_load_lds (16B/lane).
// XOR swizzle: logical k-chunk c (16B granule) of row r stored at slot c^(r&7).
#define STAGE_TILE(SRC, LD, LDSARR)                                            \
  do {                                                                         \
    _Pragma("unroll") for (int i_ = 0; i_ < 4; ++i_) {                         \
      int e_ = tid + (i_ << 8);                                                \
      int r_ = e_ >> 3;                                                        \
      int c_ = (e_ & 7) ^ (r_ & 7);                                            \
      __builtin_amdgcn_global_load_lds(                                        \
          (const __attribute__((address_space(1))) unsigned int*)((SRC) +      \
              (size_t)r_ * (LD) + (c_ << 3)),                                  \
          (__attribute__((address_space(3))) unsigned int*)(&(LDSARR)[e_ << 3]),\
          16, 0, 0);                                                           \
    }                                                                          \
  } while (0)

// Fragment read: row in [0,128), KS in {0,1}; logical chunk = KS*4+quad,
// stored at (KS*4+quad)^(row&7). Element offset = row*64 + chunk*8.
#define FRAG(LDSARR, ROW, KS)                                                  \
  (*(const short8*)(&(LDSARR)[(((ROW) << 6)) +                                 \
      ((((((KS) << 2) + quad)) ^ ((ROW) & 7)) << 3)]))

// ---------------------------------------------------------------------------
// B staging from fp32 W[k][n]: ISSUE phase loads 32 dwords (8 k x 4 groups,
// every instruction = 64 consecutive n = 256B coalesced) into 32 DISTINCT
// registers; WRITE phase (an iteration later) cvt_pk's and ds_write_b128's
// into the swizzled BT[n][k] tile. All fB indices are compile-time.
// ---------------------------------------------------------------------------
template <int LDW>
__device__ __forceinline__ void b_issue(const float* __restrict__ Wp,
                                        float* fB, int n, int octb) {
#pragma unroll
  for (int g = 0; g < 4; ++g) {
    const int oct = octb + 2 * g;                            // wave-uniform
    const float* src = Wp + (size_t)(oct << 3) * LDW + n;
#pragma unroll
    for (int j = 0; j < 8; ++j) fB[g * 8 + j] = src[(size_t)j * LDW];
  }
}

__device__ __forceinline__ void b_write(unsigned short* Bs, const float* fB,
                                        int n, int octb) {
#pragma unroll
  for (int g = 0; g < 4; ++g) {
    const int oct = octb + 2 * g;
    uint4 p;
    p.x = cvt_pk_bf16(fB[g * 8 + 0], fB[g * 8 + 1]);
    p.y = cvt_pk_bf16(fB[g * 8 + 2], fB[g * 8 + 3]);
    p.z = cvt_pk_bf16(fB[g * 8 + 4], fB[g * 8 + 5]);
    p.w = cvt_pk_bf16(fB[g * 8 + 6], fB[g * 8 + 7]);
    *(uint4*)(&Bs[(n << 6) + ((oct ^ (n & 7)) << 3)]) = p;
  }
}

// ---------------- tiny streaming convert: x,z fp32 -> bf16 -----------------
__global__ __launch_bounds__(256) void convert_xz(const float* __restrict__ x,
                                                  const float* __restrict__ z,
                                                  unsigned short* __restrict__ xb,
                                                  unsigned short* __restrict__ zb) {
  int idx = (blockIdx.x * 256 + threadIdx.x) * 8;   // 192 blocks: 393216 elems
  const float* src;
  unsigned short* dst;
  if (idx < 262144) { src = x + idx; dst = xb + idx; }
  else              { src = z + (idx - 262144); dst = zb + (idx - 262144); }
  float4 f0 = *(const float4*)src;
  float4 f1 = *(const float4*)(src + 4);
  uint4 p;
  p.x = f2bf(f0.x) | ((unsigned)f2bf(f0.y) << 16);
  p.y = f2bf(f0.z) | ((unsigned)f2bf(f0.w) << 16);
  p.z = f2bf(f1.x) | ((unsigned)f2bf(f1.y) << 16);
  p.w = f2bf(f1.z) | ((unsigned)f2bf(f1.w) << 16);
  *(uint4*)dst = p;
}

// ---------------- fused QKV gemm: C_bf16 = A_bf16 * W_f32 + bias -----------
// grid (1024, 1, 3). Remap: xcd=id&7, j=id>>3; m=j&3; n-panel=xcd*32+(j>>2):
// the 4 m-blocks sharing a weight n-panel run on ONE XCD concurrently, so
// the fp32 panel is fetched from HBM once and L2-hit 3 times.
__global__ __launch_bounds__(256, 2) void gemm_qkv(const unsigned short* __restrict__ xb,
                                                   const unsigned short* __restrict__ zb,
                                                   const float* __restrict__ Wq,
                                                   const float* __restrict__ Wk,
                                                   const float* __restrict__ Wv,
                                                   const float* __restrict__ bq,
                                                   const float* __restrict__ bk,
                                                   const float* __restrict__ bv,
                                                   unsigned short* __restrict__ Qb,
                                                   unsigned short* __restrict__ Kb,
                                                   unsigned short* __restrict__ Vb) {
  __shared__ __align__(16) unsigned short As[2][128 * 64];
  __shared__ __align__(16) unsigned short Bs[2][128 * 64];
  const int tid = threadIdx.x;
  const int zsel = blockIdx.z;
  const unsigned short* A;
  const float* W;
  const float* bias;
  unsigned short* C;
  int Ka;
  if (zsel == 0)      { A = zb; W = Wq; bias = bq; C = Qb; Ka = 256; }
  else if (zsel == 1) { A = xb; W = Wk; bias = bk; C = Kb; Ka = 512; }
  else                { A = xb; W = Wv; bias = bv; C = Vb; Ka = 512; }
  const int id = blockIdx.x;
  const int xcd = id & 7, bj = id >> 3;
  const int m0 = (bj & 3) << 7;
  const int n0 = ((xcd << 5) | (bj >> 2)) << 7;
  const int lane = tid & 63, wid = tid >> 6;
  const int quad = lane >> 4, l15 = lane & 15;
  const int wm = wid >> 1, wn = wid & 1;
  const int n = tid & 127;
  const int octb = __builtin_amdgcn_readfirstlane(tid >> 7);
  const int nsteps = Ka >> 6;

  float fB[32];
  floatx4 acc[4][4] = {};
  int c = 0;
  STAGE_TILE(A + (size_t)m0 * Ka, Ka, As[0]);
  b_issue<32768>(W + n0, fB, n, octb);
  for (int t = 0; t < nsteps; ++t) {
    b_write(Bs[c], fB, n, octb);         // waits vmcnt for fB (drains A-DMA too)
    __syncthreads();                     // tile t published
    if (t + 1 < nsteps) {                // prefetch t+1: in flight across MFMA
      STAGE_TILE(A + (size_t)m0 * Ka + ((t + 1) << 6), Ka, As[c ^ 1]);
      b_issue<32768>(W + ((size_t)(t + 1) << 6) * 32768 + n0, fB, n, octb);
    }
    __builtin_amdgcn_sched_barrier(0);   // pin prefetch issue before compute
#pragma unroll
    for (int ks = 0; ks < 2; ++ks) {
      short8 aF[4], bF[4];
#pragma unroll
      for (int mi = 0; mi < 4; ++mi) aF[mi] = FRAG(As[c], wm * 64 + mi * 16 + l15, ks);
#pragma unroll
      for (int ni = 0; ni < 4; ++ni) bF[ni] = FRAG(Bs[c], wn * 64 + ni * 16 + l15, ks);
#pragma unroll
      for (int mi = 0; mi < 4; ++mi)
#pragma unroll
        for (int ni = 0; ni < 4; ++ni)
          acc[mi][ni] = MFMA16(aF[mi], bF[ni], acc[mi][ni]);
    }
    c ^= 1;
  }
#pragma unroll
  for (int ni = 0; ni < 4; ++ni) {
    int col = n0 + wn * 64 + ni * 16 + l15;
    float bv2 = bias[col];
#pragma unroll
    for (int mi = 0; mi < 4; ++mi) {
      int row = m0 + wm * 64 + mi * 16 + (quad << 2);
#pragma unroll
      for (int r = 0; r < 4; ++r)
        C[(size_t)(row + r) * 32768 + col] = f2bf(acc[mi][ni][r] + bv2);
    }
  }
}

// ---------------- attention: one block per (bn, h), 64x64 tiles ------------
__global__ __launch_bounds__(256) void attn64(const unsigned short* __restrict__ Qb,
                                              const unsigned short* __restrict__ Kb,
                                              const unsigned short* __restrict__ Vb,
                                              unsigned short* __restrict__ Ob) {
  __shared__ __align__(16) unsigned short Qs[64 * 72];
  __shared__ __align__(16) unsigned short Ks[64 * 72];
  __shared__ __align__(16) unsigned short VT[64 * 72];
  __shared__ __align__(16) unsigned short Ps[64 * 72];
  const int tid = threadIdx.x;
  const int bn = blockIdx.x >> 3, h = blockIdx.x & 7;
  const size_t base = (size_t)bn * 32768 + (size_t)h * 4096;
  const unsigned short* q = Qb + base;
  const unsigned short* k = Kb + base;
  const unsigned short* v = Vb + base;
#pragma unroll
  for (int i = 0; i < 2; ++i) {
    int e = tid + (i << 8);
    int r = e >> 3, dblk = e & 7;
    *(uint4*)(&Qs[r * 72 + dblk * 8]) = *(const uint4*)(q + r * 64 + dblk * 8);
    *(uint4*)(&Ks[r * 72 + dblk * 8]) = *(const uint4*)(k + r * 64 + dblk * 8);
    uint4 vv = *(const uint4*)(v + r * 64 + dblk * 8);
    const unsigned short* pv = (const unsigned short*)&vv;
#pragma unroll
    for (int j = 0; j < 8; ++j)
      VT[(dblk * 8 + j) * 72 + r] = pv[j];
  }
  __syncthreads();
  const int lane = tid & 63, wid = tid >> 6;
  const int quad = lane >> 4, l15 = lane & 15;
  const int qs = wid << 4;
  short8 aq0 = *(const short8*)(&Qs[(qs + l15) * 72 + quad * 8]);
  short8 aq1 = *(const short8*)(&Qs[(qs + l15) * 72 + 32 + quad * 8]);
  floatx4 s[4] = {};
#pragma unroll
  for (int ni = 0; ni < 4; ++ni) {
    short8 b0 = *(const short8*)(&Ks[(ni * 16 + l15) * 72 + quad * 8]);
    short8 b1 = *(const short8*)(&Ks[(ni * 16 + l15) * 72 + 32 + quad * 8]);
    s[ni] = MFMA16(aq0, b0, s[ni]);
    s[ni] = MFMA16(aq1, b1, s[ni]);
  }
#pragma unroll
  for (int r = 0; r < 4; ++r) {
    float e0 = s[0][r] * 0.125f, e1 = s[1][r] * 0.125f;
    float e2 = s[2][r] * 0.125f, e3 = s[3][r] * 0.125f;
    float m = fmaxf(fmaxf(e0, e1), fmaxf(e2, e3));
    m = fmaxf(m, __shfl_xor(m, 1));
    m = fmaxf(m, __shfl_xor(m, 2));
    m = fmaxf(m, __shfl_xor(m, 4));
    m = fmaxf(m, __shfl_xor(m, 8));
    float x0 = __expf(e0 - m), x1 = __expf(e1 - m);
    float x2 = __expf(e2 - m), x3 = __expf(e3 - m);
    float t = x0 + x1 + x2 + x3;
    t += __shfl_xor(t, 1); t += __shfl_xor(t, 2);
    t += __shfl_xor(t, 4); t += __shfl_xor(t, 8);
    float inv = __builtin_amdgcn_rcpf(t);
    int row = qs + (quad << 2) + r;
    Ps[row * 72 +      l15] = f2bf(x0 * inv);
    Ps[row * 72 + 16 + l15] = f2bf(x1 * inv);
    Ps[row * 72 + 32 + l15] = f2bf(x2 * inv);
    Ps[row * 72 + 48 + l15] = f2bf(x3 * inv);
  }
  __syncthreads();
  short8 ap0 = *(const short8*)(&Ps[(qs + l15) * 72 + quad * 8]);
  short8 ap1 = *(const short8*)(&Ps[(qs + l15) * 72 + 32 + quad * 8]);
  floatx4 o[4] = {};
#pragma unroll
  for (int ni = 0; ni < 4; ++ni) {
    short8 b0 = *(const short8*)(&VT[(ni * 16 + l15) * 72 + quad * 8]);
    short8 b1 = *(const short8*)(&VT[(ni * 16 + l15) * 72 + 32 + quad * 8]);
    o[ni] = MFMA16(ap0, b0, o[ni]);
    o[ni] = MFMA16(ap1, b1, o[ni]);
  }
  unsigned short* outp = Ob + base;
#pragma unroll
  for (int ni = 0; ni < 4; ++ni)
#pragma unroll
    for (int r = 0; r < 4; ++r)
      outp[(qs + (quad << 2) + r) * 64 + ni * 16 + l15] = f2bf(o[ni][r]);
}

// ---------------- out gemm: Cp[ks][512][512] = Ob * Wo_f32 (partials) ------
// grid (512). Remap: xcd=id&7, j=id>>3: m=j&3, q=j>>2 (0..15): n=q&3,
// ks=xcd*4+(q>>2). The 4 m-blocks sharing a (n,ks) Wo chunk sit on one XCD.
// Plain fp32 stores to per-slice partial tiles; reduce_out sums them.
__global__ __launch_bounds__(256, 2) void gemm_out(const unsigned short* __restrict__ A,
                                                   const float* __restrict__ Wo,
                                                   float* __restrict__ Cp) {
  __shared__ __align__(16) unsigned short As[2][128 * 64];
  __shared__ __align__(16) unsigned short Bs[2][128 * 64];
  const int tid = threadIdx.x;
  const int id = blockIdx.x;
  const int xcd = id & 7, bj = id >> 3;
  const int m0 = (bj & 3) << 7;
  const int q = bj >> 2;
  const int n0 = (q & 3) << 7;
  const int ks = (xcd << 2) | (q >> 2);
  const int kbase = ks << 10;
  const int lane = tid & 63, wid = tid >> 6;
  const int quad = lane >> 4, l15 = lane & 15;
  const int wm = wid >> 1, wn = wid & 1;
  const int n = tid & 127;
  const int octb = __builtin_amdgcn_readfirstlane(tid >> 7);

  float fB[32];
  floatx4 acc[4][4] = {};
  int c = 0;
  STAGE_TILE(A + (size_t)m0 * 32768 + kbase, 32768, As[0]);
  b_issue<512>(Wo + (size_t)kbase * 512 + n0, fB, n, octb);
  for (int t = 0; t < 16; ++t) {
    b_write(Bs[c], fB, n, octb);
    __syncthreads();
    if (t + 1 < 16) {
      STAGE_TILE(A + (size_t)m0 * 32768 + kbase + ((t + 1) << 6), 32768, As[c ^ 1]);
      b_issue<512>(Wo + (size_t)(kbase + ((t + 1) << 6)) * 512 + n0, fB, n, octb);
    }
    __builtin_amdgcn_sched_barrier(0);
#pragma unroll
    for (int kss = 0; kss < 2; ++kss) {
      short8 aF[4], bF[4];
#pragma unroll
      for (int mi = 0; mi < 4; ++mi) aF[mi] = FRAG(As[c], wm * 64 + mi * 16 + l15, kss);
#pragma unroll
      for (int ni = 0; ni < 4; ++ni) bF[ni] = FRAG(Bs[c], wn * 64 + ni * 16 + l15, kss);
#pragma unroll
      for (int mi = 0; mi < 4; ++mi)
#pragma unroll
        for (int ni = 0; ni < 4; ++ni)
          acc[mi][ni] = MFMA16(aF[mi], bF[ni], acc[mi][ni]);
    }
    c ^= 1;
  }
  float* outp = Cp + (size_t)ks * 262144;
#pragma unroll
  for (int ni = 0; ni < 4; ++ni) {
    int col = n0 + wn * 64 + ni * 16 + l15;
#pragma unroll
    for (int mi = 0; mi < 4; ++mi) {
      int row = m0 + wm * 64 + mi * 16 + (quad << 2);
#pragma unroll
      for (int r = 0; r < 4; ++r)
        outp[(size_t)(row + r) * 512 + col] = acc[mi][ni][r];
    }
  }
}

// ---------------- reduce 32 partial tiles + bias -> out --------------------
__global__ __launch_bounds__(256) void reduce_out(const float* __restrict__ Cp,
                                                  const float* __restrict__ bias,
                                                  float* __restrict__ C) {
  int idx = blockIdx.x * 256 + threadIdx.x;   // grid 1024 -> 262144 outputs
  float s = bias[idx & 511];
#pragma unroll
  for (int k = 0; k < 32; ++k) s += Cp[(size_t)k * 262144 + idx];
  C[idx] = s;
}

extern "C" void kernel_launch(void* const* d_in, const int* in_sizes, int n_in,
                              void* d_out, int out_size, void* d_ws, size_t ws_size,
                              hipStream_t stream) {
  const float* x  = (const float*)d_in[0];
  const float* z  = (const float*)d_in[1];
  const float* Wq = (const float*)d_in[2];
  const float* bq = (const float*)d_in[3];
  const float* Wk = (const float*)d_in[4];
  const float* bk = (const float*)d_in[5];
  const float* Wv = (const float*)d_in[6];
  const float* bv = (const float*)d_in[7];
  const float* Wo = (const float*)d_in[8];
  const float* bo = (const float*)d_in[9];
  float* out = (float*)d_out;
  char* ws = (char*)d_ws;

  unsigned short* Qb = (unsigned short*)(ws + 0);
  unsigned short* Kb = (unsigned short*)(ws + 33554432);
  unsigned short* Vb = (unsigned short*)(ws + 67108864);
  unsigned short* Ob = (unsigned short*)(ws + 100663296);
  unsigned short* xb = (unsigned short*)(ws + 134217728);
  unsigned short* zb = (unsigned short*)(ws + 134742016);
  float*          Cp = (float*)(ws + 135266304);            // 32MB partials

  convert_xz<<<dim3(192), 256, 0, stream>>>(x, z, xb, zb);

  gemm_qkv<<<dim3(1024, 1, 3), 256, 0, stream>>>(xb, zb, Wq, Wk, Wv,
                                                 bq, bk, bv, Qb, Kb, Vb);

  attn64<<<dim3(4096), 256, 0, stream>>>(Qb, Kb, Vb, Ob);

  gemm_out<<<dim3(512), 256, 0, stream>>>(Ob, Wo, Cp);

  reduce_out<<<dim3(1024), 256, 0, stream>>>(Cp, bo, out);
}

// Round 4
// 346.645 us; speedup vs baseline: 1.1098x; 1.0105x over previous
//
#include <hip/hip_runtime.h>
#include <stdint.h>

// ---------------------------------------------------------------------------
// MultiHeadAttnCoupling: B=4 N=128 -> BN=512 rows
//   Q = z(512x256) @ Wq(256x32768) + bq
//   K = x(512x512) @ Wk(512x32768) + bk ; V likewise
//   per (bn, h in 0..7): S = Q64x64 K^T /8 ; P=softmax(S); O = P V
//   out = O(512x32768) @ Wo(32768x512) + bo   (fp32 out)
//
// v4: B-staging pipelined TWO K-steps deep across RAW barriers.
//   - __syncthreads() (which drains vmcnt(0)) replaced by
//     s_waitcnt lgkmcnt(0) + __builtin_amdgcn_s_barrier().
//   - two B register sets fB0/fB1, loop unrolled x2 (all reg indices static).
//   - counted s_waitcnt vmcnt(32) at step top: drains exactly the oldest
//     36 VMEM ops (32 B-loads + 4 A-DMA of the tile being published),
//     leaving the next tile's 32 B-loads in flight across the barrier and
//     the MFMA phase (~2 steps of latency cover). Last step uses vmcnt(0).
//   - VMEM issue order pinned with sched_barrier(0):
//     [fB(t+1) from prev iter] < [A-DMA(t+1), early] < [fB(t+2), after MFMA]
//
// ws layout (bytes):
//   Qb@0 (32M) Kb@32M Vb@64M Ob@96M  xb@128M(512K) zb@+512K(256K)
//   Cp@129M (32 partial C tiles, 32MB)  -> total 161MB
// ---------------------------------------------------------------------------

typedef __attribute__((ext_vector_type(8))) short short8;
typedef __attribute__((ext_vector_type(4))) float floatx4;

__device__ __forceinline__ unsigned short f2bf(float f) {
  union { float f; unsigned int u; } v; v.f = f;
  unsigned int u = v.u + 0x7FFFu + ((v.u >> 16) & 1u);   // round-to-nearest-even
  return (unsigned short)(u >> 16);
}

// pack two fp32 -> two bf16 in one u32 (lo = first elem), RNE.
__device__ __forceinline__ unsigned int cvt_pk_bf16(float lo, float hi) {
  unsigned int r;
  asm("v_cvt_pk_bf16_f32 %0, %1, %2" : "=v"(r) : "v"(lo), "v"(hi));
  return r;
}

#define MFMA16(a, b, c) __builtin_amdgcn_mfma_f32_16x16x32_bf16((a), (b), (c), 0, 0, 0)

// Stage a 128-row x 64-k bf16 tile into LDS via global_load_lds (16B/lane).
// XOR swizzle: logical k-chunk c (16B granule) of row r stored at slot c^(r&7).
#define STAGE_TILE(SRC, LD, LDSARR)                                            \
  do {                                                                         \
    _Pragma("unroll") for (int i_ = 0; i_ < 4; ++i_) {                         \
      int e_ = tid + (i_ << 8);                                                \
      int r_ = e_ >> 3;                                                        \
      int c_ = (e_ & 7) ^ (r_ & 7);                                            \
      __builtin_amdgcn_global_load_lds(                                        \
          (const __attribute__((address_space(1))) unsigned int*)((SRC) +      \
              (size_t)r_ * (LD) + (c_ << 3)),                                  \
          (__attribute__((address_space(3))) unsigned int*)(&(LDSARR)[e_ << 3]),\
          16, 0, 0);                                                           \
    }                                                                          \
  } while (0)

// Fragment read: row in [0,128), KS in {0,1}; logical chunk = KS*4+quad,
// stored at (KS*4+quad)^(row&7). Element offset = row*64 + chunk*8.
#define FRAG(LDSARR, ROW, KS)                                                  \
  (*(const short8*)(&(LDSARR)[(((ROW) << 6)) +                                 \
      ((((((KS) << 2) + quad)) ^ ((ROW) & 7)) << 3)]))

// ---------------------------------------------------------------------------
// B staging from fp32 W[k][n]: ISSUE loads 32 dwords (8 k x 4 wave-uniform
// octets; every instruction = 64 consecutive n = 256B coalesced) into 32
// DISTINCT registers; WRITE (two iterations later) cvt_pk's and
// ds_write_b128's into the swizzled BT[n][k] tile. All indices static.
// ---------------------------------------------------------------------------
template <int LDW>
__device__ __forceinline__ void b_issue(const float* __restrict__ Wp,
                                        float* fB, int n, int octb) {
#pragma unroll
  for (int g = 0; g < 4; ++g) {
    const int oct = octb + 2 * g;                            // wave-uniform
    const float* src = Wp + (size_t)(oct << 3) * LDW + n;
#pragma unroll
    for (int j = 0; j < 8; ++j) fB[g * 8 + j] = src[(size_t)j * LDW];
  }
}

__device__ __forceinline__ void b_write(unsigned short* Bs, const float* fB,
                                        int n, int octb) {
#pragma unroll
  for (int g = 0; g < 4; ++g) {
    const int oct = octb + 2 * g;
    uint4 p;
    p.x = cvt_pk_bf16(fB[g * 8 + 0], fB[g * 8 + 1]);
    p.y = cvt_pk_bf16(fB[g * 8 + 2], fB[g * 8 + 3]);
    p.z = cvt_pk_bf16(fB[g * 8 + 4], fB[g * 8 + 5]);
    p.w = cvt_pk_bf16(fB[g * 8 + 6], fB[g * 8 + 7]);
    *(uint4*)(&Bs[(n << 6) + ((oct ^ (n & 7)) << 3)]) = p;
  }
}

// ---------------- tiny streaming convert: x,z fp32 -> bf16 -----------------
__global__ __launch_bounds__(256) void convert_xz(const float* __restrict__ x,
                                                  const float* __restrict__ z,
                                                  unsigned short* __restrict__ xb,
                                                  unsigned short* __restrict__ zb) {
  int idx = (blockIdx.x * 256 + threadIdx.x) * 8;   // 192 blocks: 393216 elems
  const float* src;
  unsigned short* dst;
  if (idx < 262144) { src = x + idx; dst = xb + idx; }
  else              { src = z + (idx - 262144); dst = zb + (idx - 262144); }
  float4 f0 = *(const float4*)src;
  float4 f1 = *(const float4*)(src + 4);
  uint4 p;
  p.x = f2bf(f0.x) | ((unsigned)f2bf(f0.y) << 16);
  p.y = f2bf(f0.z) | ((unsigned)f2bf(f0.w) << 16);
  p.z = f2bf(f1.x) | ((unsigned)f2bf(f1.y) << 16);
  p.w = f2bf(f1.z) | ((unsigned)f2bf(f1.w) << 16);
  *(uint4*)dst = p;
}

// ---------------- fused QKV gemm: C_bf16 = A_bf16 * W_f32 + bias -----------
// grid (1024, 1, 3). Remap: xcd=id&7, j=id>>3; m=j&3; n-panel=xcd*32+(j>>2):
// the 4 m-blocks sharing a weight n-panel run on ONE XCD concurrently, so
// the fp32 panel is fetched from HBM once and L2-hit 3 times.
__global__ __launch_bounds__(256, 2) void gemm_qkv(const unsigned short* __restrict__ xb,
                                                   const unsigned short* __restrict__ zb,
                                                   const float* __restrict__ Wq,
                                                   const float* __restrict__ Wk,
                                                   const float* __restrict__ Wv,
                                                   const float* __restrict__ bq,
                                                   const float* __restrict__ bk,
                                                   const float* __restrict__ bv,
                                                   unsigned short* __restrict__ Qb,
                                                   unsigned short* __restrict__ Kb,
                                                   unsigned short* __restrict__ Vb) {
  __shared__ __align__(16) unsigned short As0[128 * 64], As1[128 * 64];
  __shared__ __align__(16) unsigned short Bs0[128 * 64], Bs1[128 * 64];
  const int tid = threadIdx.x;
  const int zsel = blockIdx.z;
  const unsigned short* A;
  const float* W;
  const float* bias;
  unsigned short* C;
  int Ka;
  if (zsel == 0)      { A = zb; W = Wq; bias = bq; C = Qb; Ka = 256; }
  else if (zsel == 1) { A = xb; W = Wk; bias = bk; C = Kb; Ka = 512; }
  else                { A = xb; W = Wv; bias = bv; C = Vb; Ka = 512; }
  const int id = blockIdx.x;
  const int xcd = id & 7, bj = id >> 3;
  const int m0 = (bj & 3) << 7;
  const int n0 = ((xcd << 5) | (bj >> 2)) << 7;
  const int lane = tid & 63, wid = tid >> 6;
  const int quad = lane >> 4, l15 = lane & 15;
  const int wm = wid >> 1, wn = wid & 1;
  const int n = tid & 127;
  const int octb = __builtin_amdgcn_readfirstlane(tid >> 7);
  const int nsteps = Ka >> 6;                                // 4 or 8 (even)

  float fB0[32], fB1[32];
  floatx4 acc[4][4] = {};

  // prologue, VMEM order pinned: [fB(0) 32][A(0) 4][fB(1) 32]
  b_issue<32768>(W + n0, fB0, n, octb);
  __builtin_amdgcn_sched_barrier(0);
  STAGE_TILE(A + (size_t)m0 * Ka, Ka, As0);
  __builtin_amdgcn_sched_barrier(0);
  b_issue<32768>(W + (size_t)64 * 32768 + n0, fB1, n, octb);
  __builtin_amdgcn_sched_barrier(0);

  auto step = [&](int t, float (&fBc)[32], unsigned short* AsC,
                  unsigned short* BsC, unsigned short* AsN) {
    // oldest 36 outstanding = [fB(t) 32, A-DMA(t) 4]; keep the rest in flight
    if (t == nsteps - 1) { asm volatile("s_waitcnt vmcnt(0)" ::: "memory"); }
    else                 { asm volatile("s_waitcnt vmcnt(32)" ::: "memory"); }
    __builtin_amdgcn_sched_barrier(0);
    b_write(BsC, fBc, n, octb);
    asm volatile("s_waitcnt lgkmcnt(0)" ::: "memory");
    __builtin_amdgcn_s_barrier();                 // publish As[t], Bs[t]
    __builtin_amdgcn_sched_barrier(0);
    if (t + 1 < nsteps)                            // A-DMA(t+1): early issue
      STAGE_TILE(A + (size_t)m0 * Ka + ((t + 1) << 6), Ka, AsN);
    __builtin_amdgcn_sched_barrier(0);
#pragma unroll
    for (int ks = 0; ks < 2; ++ks) {
      short8 aF[4], bF[4];
#pragma unroll
      for (int mi = 0; mi < 4; ++mi) aF[mi] = FRAG(AsC, wm * 64 + mi * 16 + l15, ks);
#pragma unroll
      for (int ni = 0; ni < 4; ++ni) bF[ni] = FRAG(BsC, wn * 64 + ni * 16 + l15, ks);
#pragma unroll
      for (int mi = 0; mi < 4; ++mi)
#pragma unroll
        for (int ni = 0; ni < 4; ++ni)
          acc[mi][ni] = MFMA16(aF[mi], bF[ni], acc[mi][ni]);
    }
    __builtin_amdgcn_sched_barrier(0);
    if (t + 2 < nsteps)                            // fB(t+2): issue last
      b_issue<32768>(W + ((size_t)(t + 2) << 6) * 32768 + n0, fBc, n, octb);
    __builtin_amdgcn_sched_barrier(0);
  };
  for (int t = 0; t < nsteps; t += 2) {            // nsteps even: no tail
    step(t,     fB0, As0, Bs0, As1);
    step(t + 1, fB1, As1, Bs1, As0);
  }
#pragma unroll
  for (int ni = 0; ni < 4; ++ni) {
    int col = n0 + wn * 64 + ni * 16 + l15;
    float bv2 = bias[col];
#pragma unroll
    for (int mi = 0; mi < 4; ++mi) {
      int row = m0 + wm * 64 + mi * 16 + (quad << 2);
#pragma unroll
      for (int r = 0; r < 4; ++r)
        C[(size_t)(row + r) * 32768 + col] = f2bf(acc[mi][ni][r] + bv2);
    }
  }
}

// ---------------- attention: one block per (bn, h), 64x64 tiles ------------
__global__ __launch_bounds__(256) void attn64(const unsigned short* __restrict__ Qb,
                                              const unsigned short* __restrict__ Kb,
                                              const unsigned short* __restrict__ Vb,
                                              unsigned short* __restrict__ Ob) {
  __shared__ __align__(16) unsigned short Qs[64 * 72];
  __shared__ __align__(16) unsigned short Ks[64 * 72];
  __shared__ __align__(16) unsigned short VT[64 * 72];
  __shared__ __align__(16) unsigned short Ps[64 * 72];
  const int tid = threadIdx.x;
  const int bn = blockIdx.x >> 3, h = blockIdx.x & 7;
  const size_t base = (size_t)bn * 32768 + (size_t)h * 4096;
  const unsigned short* q = Qb + base;
  const unsigned short* k = Kb + base;
  const unsigned short* v = Vb + base;
#pragma unroll
  for (int i = 0; i < 2; ++i) {
    int e = tid + (i << 8);
    int r = e >> 3, dblk = e & 7;
    *(uint4*)(&Qs[r * 72 + dblk * 8]) = *(const uint4*)(q + r * 64 + dblk * 8);
    *(uint4*)(&Ks[r * 72 + dblk * 8]) = *(const uint4*)(k + r * 64 + dblk * 8);
    uint4 vv = *(const uint4*)(v + r * 64 + dblk * 8);
    const unsigned short* pv = (const unsigned short*)&vv;
#pragma unroll
    for (int j = 0; j < 8; ++j)
      VT[(dblk * 8 + j) * 72 + r] = pv[j];
  }
  __syncthreads();
  const int lane = tid & 63, wid = tid >> 6;
  const int quad = lane >> 4, l15 = lane & 15;
  const int qs = wid << 4;
  short8 aq0 = *(const short8*)(&Qs[(qs + l15) * 72 + quad * 8]);
  short8 aq1 = *(const short8*)(&Qs[(qs + l15) * 72 + 32 + quad * 8]);
  floatx4 s[4] = {};
#pragma unroll
  for (int ni = 0; ni < 4; ++ni) {
    short8 b0 = *(const short8*)(&Ks[(ni * 16 + l15) * 72 + quad * 8]);
    short8 b1 = *(const short8*)(&Ks[(ni * 16 + l15) * 72 + 32 + quad * 8]);
    s[ni] = MFMA16(aq0, b0, s[ni]);
    s[ni] = MFMA16(aq1, b1, s[ni]);
  }
#pragma unroll
  for (int r = 0; r < 4; ++r) {
    float e0 = s[0][r] * 0.125f, e1 = s[1][r] * 0.125f;
    float e2 = s[2][r] * 0.125f, e3 = s[3][r] * 0.125f;
    float m = fmaxf(fmaxf(e0, e1), fmaxf(e2, e3));
    m = fmaxf(m, __shfl_xor(m, 1));
    m = fmaxf(m, __shfl_xor(m, 2));
    m = fmaxf(m, __shfl_xor(m, 4));
    m = fmaxf(m, __shfl_xor(m, 8));
    float x0 = __expf(e0 - m), x1 = __expf(e1 - m);
    float x2 = __expf(e2 - m), x3 = __expf(e3 - m);
    float t = x0 + x1 + x2 + x3;
    t += __shfl_xor(t, 1); t += __shfl_xor(t, 2);
    t += __shfl_xor(t, 4); t += __shfl_xor(t, 8);
    float inv = __builtin_amdgcn_rcpf(t);
    int row = qs + (quad << 2) + r;
    Ps[row * 72 +      l15] = f2bf(x0 * inv);
    Ps[row * 72 + 16 + l15] = f2bf(x1 * inv);
    Ps[row * 72 + 32 + l15] = f2bf(x2 * inv);
    Ps[row * 72 + 48 + l15] = f2bf(x3 * inv);
  }
  __syncthreads();
  short8 ap0 = *(const short8*)(&Ps[(qs + l15) * 72 + quad * 8]);
  short8 ap1 = *(const short8*)(&Ps[(qs + l15) * 72 + 32 + quad * 8]);
  floatx4 o[4] = {};
#pragma unroll
  for (int ni = 0; ni < 4; ++ni) {
    short8 b0 = *(const short8*)(&VT[(ni * 16 + l15) * 72 + quad * 8]);
    short8 b1 = *(const short8*)(&VT[(ni * 16 + l15) * 72 + 32 + quad * 8]);
    o[ni] = MFMA16(ap0, b0, o[ni]);
    o[ni] = MFMA16(ap1, b1, o[ni]);
  }
  unsigned short* outp = Ob + base;
#pragma unroll
  for (int ni = 0; ni < 4; ++ni)
#pragma unroll
    for (int r = 0; r < 4; ++r)
      outp[(qs + (quad << 2) + r) * 64 + ni * 16 + l15] = f2bf(o[ni][r]);
}

// ---------------- out gemm: Cp[ks][512][512] = Ob * Wo_f32 (partials) ------
// grid (512). Remap: xcd=id&7, j=id>>3: m=j&3, q=j>>2 (0..15): n=q&3,
// ks=xcd*4+(q>>2). The 4 m-blocks sharing a (n,ks) Wo chunk sit on one XCD.
// Plain fp32 stores to per-slice partial tiles; reduce_out sums them.
// Same 2-deep pipelined staging as gemm_qkv (16 steps).
__global__ __launch_bounds__(256, 2) void gemm_out(const unsigned short* __restrict__ A,
                                                   const float* __restrict__ Wo,
                                                   float* __restrict__ Cp) {
  __shared__ __align__(16) unsigned short As0[128 * 64], As1[128 * 64];
  __shared__ __align__(16) unsigned short Bs0[128 * 64], Bs1[128 * 64];
  const int tid = threadIdx.x;
  const int id = blockIdx.x;
  const int xcd = id & 7, bj = id >> 3;
  const int m0 = (bj & 3) << 7;
  const int q = bj >> 2;
  const int n0 = (q & 3) << 7;
  const int ks = (xcd << 2) | (q >> 2);
  const int kbase = ks << 10;
  const int lane = tid & 63, wid = tid >> 6;
  const int quad = lane >> 4, l15 = lane & 15;
  const int wm = wid >> 1, wn = wid & 1;
  const int n = tid & 127;
  const int octb = __builtin_amdgcn_readfirstlane(tid >> 7);
  const int nsteps = 16;

  float fB0[32], fB1[32];
  floatx4 acc[4][4] = {};

  b_issue<512>(Wo + (size_t)kbase * 512 + n0, fB0, n, octb);
  __builtin_amdgcn_sched_barrier(0);
  STAGE_TILE(A + (size_t)m0 * 32768 + kbase, 32768, As0);
  __builtin_amdgcn_sched_barrier(0);
  b_issue<512>(Wo + (size_t)(kbase + 64) * 512 + n0, fB1, n, octb);
  __builtin_amdgcn_sched_barrier(0);

  auto step = [&](int t, float (&fBc)[32], unsigned short* AsC,
                  unsigned short* BsC, unsigned short* AsN) {
    if (t == nsteps - 1) { asm volatile("s_waitcnt vmcnt(0)" ::: "memory"); }
    else                 { asm volatile("s_waitcnt vmcnt(32)" ::: "memory"); }
    __builtin_amdgcn_sched_barrier(0);
    b_write(BsC, fBc, n, octb);
    asm volatile("s_waitcnt lgkmcnt(0)" ::: "memory");
    __builtin_amdgcn_s_barrier();
    __builtin_amdgcn_sched_barrier(0);
    if (t + 1 < nsteps)
      STAGE_TILE(A + (size_t)m0 * 32768 + kbase + ((t + 1) << 6), 32768, AsN);
    __builtin_amdgcn_sched_barrier(0);
#pragma unroll
    for (int kss = 0; kss < 2; ++kss) {
      short8 aF[4], bF[4];
#pragma unroll
      for (int mi = 0; mi < 4; ++mi) aF[mi] = FRAG(AsC, wm * 64 + mi * 16 + l15, kss);
#pragma unroll
      for (int ni = 0; ni < 4; ++ni) bF[ni] = FRAG(BsC, wn * 64 + ni * 16 + l15, kss);
#pragma unroll
      for (int mi = 0; mi < 4; ++mi)
#pragma unroll
        for (int ni = 0; ni < 4; ++ni)
          acc[mi][ni] = MFMA16(aF[mi], bF[ni], acc[mi][ni]);
    }
    __builtin_amdgcn_sched_barrier(0);
    if (t + 2 < nsteps)
      b_issue<512>(Wo + (size_t)(kbase + ((t + 2) << 6)) * 512 + n0, fBc, n, octb);
    __builtin_amdgcn_sched_barrier(0);
  };
  for (int t = 0; t < nsteps; t += 2) {
    step(t,     fB0, As0, Bs0, As1);
    step(t + 1, fB1, As1, Bs1, As0);
  }
  float* outp = Cp + (size_t)ks * 262144;
#pragma unroll
  for (int ni = 0; ni < 4; ++ni) {
    int col = n0 + wn * 64 + ni * 16 + l15;
#pragma unroll
    for (int mi = 0; mi < 4; ++mi) {
      int row = m0 + wm * 64 + mi * 16 + (quad << 2);
#pragma unroll
      for (int r = 0; r < 4; ++r)
        outp[(size_t)(row + r) * 512 + col] = acc[mi][ni][r];
    }
  }
}

// ---------------- reduce 32 partial tiles + bias -> out --------------------
__global__ __launch_bounds__(256) void reduce_out(const float* __restrict__ Cp,
                                                  const float* __restrict__ bias,
                                                  float* __restrict__ C) {
  int idx = blockIdx.x * 256 + threadIdx.x;   // grid 1024 -> 262144 outputs
  float s = bias[idx & 511];
#pragma unroll
  for (int k = 0; k < 32; ++k) s += Cp[(size_t)k * 262144 + idx];
  C[idx] = s;
}

extern "C" void kernel_launch(void* const* d_in, const int* in_sizes, int n_in,
                              void* d_out, int out_size, void* d_ws, size_t ws_size,
                              hipStream_t stream) {
  const float* x  = (const float*)d_in[0];
  const float* z  = (const float*)d_in[1];
  const float* Wq = (const float*)d_in[2];
  const float* bq = (const float*)d_in[3];
  const float* Wk = (const float*)d_in[4];
  const float* bk = (const float*)d_in[5];
  const float* Wv = (const float*)d_in[6];
  const float* bv = (const float*)d_in[7];
  const float* Wo = (const float*)d_in[8];
  const float* bo = (const float*)d_in[9];
  float* out = (float*)d_out;
  char* ws = (char*)d_ws;

  unsigned short* Qb = (unsigned short*)(ws + 0);
  unsigned short* Kb = (unsigned short*)(ws + 33554432);
  unsigned short* Vb = (unsigned short*)(ws + 67108864);
  unsigned short* Ob = (unsigned short*)(ws + 100663296);
  unsigned short* xb = (unsigned short*)(ws + 134217728);
  unsigned short* zb = (unsigned short*)(ws + 134742016);
  float*          Cp = (float*)(ws + 135266304);            // 32MB partials

  convert_xz<<<dim3(192), 256, 0, stream>>>(x, z, xb, zb);

  gemm_qkv<<<dim3(1024, 1, 3), 256, 0, stream>>>(xb, zb, Wq, Wk, Wv,
                                                 bq, bk, bv, Qb, Kb, Vb);

  attn64<<<dim3(4096), 256, 0, stream>>>(Qb, Kb, Vb, Ob);

  gemm_out<<<dim3(512), 256, 0, stream>>>(Ob, Wo, Cp);

  reduce_out<<<dim3(1024), 256, 0, stream>>>(Cp, bo, out);
}

// Round 5
// 334.133 us; speedup vs baseline: 1.1513x; 1.0374x over previous
//
#include <hip/hip_runtime.h>
#include <stdint.h>

// ---------------------------------------------------------------------------
// MultiHeadAttnCoupling: B=4 N=128 -> BN=512 rows
//   Q = z(512x256) @ Wq(256x32768) + bq
//   K = x(512x512) @ Wk(512x32768) + bk ; V likewise
//   per (bn, h in 0..7): S = Q64x64 K^T /8 ; P=softmax(S); O = P V
//   out = O(512x32768) @ Wo(32768x512) + bo   (fp32 out)
//
// v5: occupancy + robust 1-deep pipeline.
//   - LDS 48KB/block (As double-buffered 2x16KB, Bs single 16KB) -> 3
//     blocks/CU (was 2 at 64KB). __launch_bounds__(256,3), one fB set.
//   - per step: b_write(t) [auto-waits its loads] -> vmcnt(0)+lgkmcnt(0) ->
//     barrier1 (publish) -> issue A-DMA(t+1)+fB(t+1) [36 outstanding, well
//     under the 63 vmcnt limit that silently broke v4's 2-deep scheme] ->
//     MFMA(t) -> barrier2 (Bs overwrite guard). Prefetch flies across the
//     whole step (~1.5-2k cy >= HBM/L3 latency).
//
// ws layout (bytes):
//   Qb@0 (32M) Kb@32M Vb@64M Ob@96M  xb@128M(512K) zb@+512K(256K)
//   Cp@129M (32 partial C tiles, 32MB)  -> total 161MB
// ---------------------------------------------------------------------------

typedef __attribute__((ext_vector_type(8))) short short8;
typedef __attribute__((ext_vector_type(4))) float floatx4;

__device__ __forceinline__ unsigned short f2bf(float f) {
  union { float f; unsigned int u; } v; v.f = f;
  unsigned int u = v.u + 0x7FFFu + ((v.u >> 16) & 1u);   // round-to-nearest-even
  return (unsigned short)(u >> 16);
}

// pack two fp32 -> two bf16 in one u32 (lo = first elem), RNE.
__device__ __forceinline__ unsigned int cvt_pk_bf16(float lo, float hi) {
  unsigned int r;
  asm("v_cvt_pk_bf16_f32 %0, %1, %2" : "=v"(r) : "v"(lo), "v"(hi));
  return r;
}

#define MFMA16(a, b, c) __builtin_amdgcn_mfma_f32_16x16x32_bf16((a), (b), (c), 0, 0, 0)

// Stage a 128-row x 64-k bf16 tile into LDS via global_load_lds (16B/lane).
// XOR swizzle: logical k-chunk c (16B granule) of row r stored at slot c^(r&7).
#define STAGE_TILE(SRC, LD, LDSARR)                                            \
  do {                                                                         \
    _Pragma("unroll") for (int i_ = 0; i_ < 4; ++i_) {                         \
      int e_ = tid + (i_ << 8);                                                \
      int r_ = e_ >> 3;                                                        \
      int c_ = (e_ & 7) ^ (r_ & 7);                                            \
      __builtin_amdgcn_global_load_lds(                                        \
          (const __attribute__((address_space(1))) unsigned int*)((SRC) +      \
              (size_t)r_ * (LD) + (c_ << 3)),                                  \
          (__attribute__((address_space(3))) unsigned int*)(&(LDSARR)[e_ << 3]),\
          16, 0, 0);                                                           \
    }                                                                          \
  } while (0)

// Fragment read: row in [0,128), KS in {0,1}; logical chunk = KS*4+quad,
// stored at (KS*4+quad)^(row&7). Element offset = row*64 + chunk*8.
#define FRAG(LDSARR, ROW, KS)                                                  \
  (*(const short8*)(&(LDSARR)[(((ROW) << 6)) +                                 \
      ((((((KS) << 2) + quad)) ^ ((ROW) & 7)) << 3)]))

// ---------------------------------------------------------------------------
// B staging from fp32 W[k][n]: ISSUE loads 32 dwords (8 k x 4 wave-uniform
// octets; every instruction = 64 consecutive n = 256B coalesced) into 32
// DISTINCT registers; WRITE (one step later) cvt_pk's and ds_write_b128's
// into the swizzled BT[n][k] tile. All indices static.
// ---------------------------------------------------------------------------
template <int LDW>
__device__ __forceinline__ void b_issue(const float* __restrict__ Wp,
                                        float* fB, int n, int octb) {
#pragma unroll
  for (int g = 0; g < 4; ++g) {
    const int oct = octb + 2 * g;                            // wave-uniform
    const float* src = Wp + (size_t)(oct << 3) * LDW + n;
#pragma unroll
    for (int j = 0; j < 8; ++j) fB[g * 8 + j] = src[(size_t)j * LDW];
  }
}

__device__ __forceinline__ void b_write(unsigned short* Bs, const float* fB,
                                        int n, int octb) {
#pragma unroll
  for (int g = 0; g < 4; ++g) {
    const int oct = octb + 2 * g;
    uint4 p;
    p.x = cvt_pk_bf16(fB[g * 8 + 0], fB[g * 8 + 1]);
    p.y = cvt_pk_bf16(fB[g * 8 + 2], fB[g * 8 + 3]);
    p.z = cvt_pk_bf16(fB[g * 8 + 4], fB[g * 8 + 5]);
    p.w = cvt_pk_bf16(fB[g * 8 + 6], fB[g * 8 + 7]);
    *(uint4*)(&Bs[(n << 6) + ((oct ^ (n & 7)) << 3)]) = p;
  }
}

// ---------------- tiny streaming convert: x,z fp32 -> bf16 -----------------
__global__ __launch_bounds__(256) void convert_xz(const float* __restrict__ x,
                                                  const float* __restrict__ z,
                                                  unsigned short* __restrict__ xb,
                                                  unsigned short* __restrict__ zb) {
  int idx = (blockIdx.x * 256 + threadIdx.x) * 8;   // 192 blocks: 393216 elems
  const float* src;
  unsigned short* dst;
  if (idx < 262144) { src = x + idx; dst = xb + idx; }
  else              { src = z + (idx - 262144); dst = zb + (idx - 262144); }
  float4 f0 = *(const float4*)src;
  float4 f1 = *(const float4*)(src + 4);
  uint4 p;
  p.x = f2bf(f0.x) | ((unsigned)f2bf(f0.y) << 16);
  p.y = f2bf(f0.z) | ((unsigned)f2bf(f0.w) << 16);
  p.z = f2bf(f1.x) | ((unsigned)f2bf(f1.y) << 16);
  p.w = f2bf(f1.z) | ((unsigned)f2bf(f1.w) << 16);
  *(uint4*)dst = p;
}

// ---------------- fused QKV gemm: C_bf16 = A_bf16 * W_f32 + bias -----------
// grid (1024, 1, 3). Remap: xcd=id&7, j=id>>3; m=j&3; n-panel=xcd*32+(j>>2):
// the 4 m-blocks sharing a weight n-panel run on ONE XCD concurrently, so
// the fp32 panel is fetched from HBM once and L2-hit 3 times.
__global__ __launch_bounds__(256, 3) void gemm_qkv(const unsigned short* __restrict__ xb,
                                                   const unsigned short* __restrict__ zb,
                                                   const float* __restrict__ Wq,
                                                   const float* __restrict__ Wk,
                                                   const float* __restrict__ Wv,
                                                   const float* __restrict__ bq,
                                                   const float* __restrict__ bk,
                                                   const float* __restrict__ bv,
                                                   unsigned short* __restrict__ Qb,
                                                   unsigned short* __restrict__ Kb,
                                                   unsigned short* __restrict__ Vb) {
  __shared__ __align__(16) unsigned short As[2][128 * 64];   // 32 KB
  __shared__ __align__(16) unsigned short Bs[128 * 64];      // 16 KB
  const int tid = threadIdx.x;
  const int zsel = blockIdx.z;
  const unsigned short* A;
  const float* W;
  const float* bias;
  unsigned short* C;
  int Ka;
  if (zsel == 0)      { A = zb; W = Wq; bias = bq; C = Qb; Ka = 256; }
  else if (zsel == 1) { A = xb; W = Wk; bias = bk; C = Kb; Ka = 512; }
  else                { A = xb; W = Wv; bias = bv; C = Vb; Ka = 512; }
  const int id = blockIdx.x;
  const int xcd = id & 7, bj = id >> 3;
  const int m0 = (bj & 3) << 7;
  const int n0 = ((xcd << 5) | (bj >> 2)) << 7;
  const int lane = tid & 63, wid = tid >> 6;
  const int quad = lane >> 4, l15 = lane & 15;
  const int wm = wid >> 1, wn = wid & 1;
  const int n = tid & 127;
  const int octb = __builtin_amdgcn_readfirstlane(tid >> 7);
  const int nsteps = Ka >> 6;                                // 4 or 8

  float fB[32];
  floatx4 acc[4][4] = {};

  // prologue: A(0)-DMA then fB(0); fB newest so its auto-wait drains both.
  STAGE_TILE(A + (size_t)m0 * Ka, Ka, As[0]);
  __builtin_amdgcn_sched_barrier(0);
  b_issue<32768>(W + n0, fB, n, octb);
  __builtin_amdgcn_sched_barrier(0);

  for (int t = 0; t < nsteps; ++t) {
    const int cur = t & 1;
    b_write(Bs, fB, n, octb);            // auto s_waitcnt for fB(t)
    asm volatile("s_waitcnt vmcnt(0) lgkmcnt(0)" ::: "memory");
    __builtin_amdgcn_s_barrier();        // barrier1: publish As[cur], Bs
    __builtin_amdgcn_sched_barrier(0);
    if (t + 1 < nsteps) {                // prefetch t+1: flies across step
      STAGE_TILE(A + (size_t)m0 * Ka + ((t + 1) << 6), Ka, As[cur ^ 1]);
      __builtin_amdgcn_sched_barrier(0);
      b_issue<32768>(W + ((size_t)(t + 1) << 6) * 32768 + n0, fB, n, octb);
    }
    __builtin_amdgcn_sched_barrier(0);
#pragma unroll
    for (int ks = 0; ks < 2; ++ks) {
      short8 aF[4], bF[4];
#pragma unroll
      for (int mi = 0; mi < 4; ++mi) aF[mi] = FRAG(As[cur], wm * 64 + mi * 16 + l15, ks);
#pragma unroll
      for (int ni = 0; ni < 4; ++ni) bF[ni] = FRAG(Bs, wn * 64 + ni * 16 + l15, ks);
#pragma unroll
      for (int mi = 0; mi < 4; ++mi)
#pragma unroll
        for (int ni = 0; ni < 4; ++ni)
          acc[mi][ni] = MFMA16(aF[mi], bF[ni], acc[mi][ni]);
    }
    __builtin_amdgcn_s_barrier();        // barrier2: Bs overwrite guard
  }
#pragma unroll
  for (int ni = 0; ni < 4; ++ni) {
    int col = n0 + wn * 64 + ni * 16 + l15;
    float bv2 = bias[col];
#pragma unroll
    for (int mi = 0; mi < 4; ++mi) {
      int row = m0 + wm * 64 + mi * 16 + (quad << 2);
#pragma unroll
      for (int r = 0; r < 4; ++r)
        C[(size_t)(row + r) * 32768 + col] = f2bf(acc[mi][ni][r] + bv2);
    }
  }
}

// ---------------- attention: one block per (bn, h), 64x64 tiles ------------
__global__ __launch_bounds__(256) void attn64(const unsigned short* __restrict__ Qb,
                                              const unsigned short* __restrict__ Kb,
                                              const unsigned short* __restrict__ Vb,
                                              unsigned short* __restrict__ Ob) {
  __shared__ __align__(16) unsigned short Qs[64 * 72];
  __shared__ __align__(16) unsigned short Ks[64 * 72];
  __shared__ __align__(16) unsigned short VT[64 * 72];
  __shared__ __align__(16) unsigned short Ps[64 * 72];
  const int tid = threadIdx.x;
  const int bn = blockIdx.x >> 3, h = blockIdx.x & 7;
  const size_t base = (size_t)bn * 32768 + (size_t)h * 4096;
  const unsigned short* q = Qb + base;
  const unsigned short* k = Kb + base;
  const unsigned short* v = Vb + base;
#pragma unroll
  for (int i = 0; i < 2; ++i) {
    int e = tid + (i << 8);
    int r = e >> 3, dblk = e & 7;
    *(uint4*)(&Qs[r * 72 + dblk * 8]) = *(const uint4*)(q + r * 64 + dblk * 8);
    *(uint4*)(&Ks[r * 72 + dblk * 8]) = *(const uint4*)(k + r * 64 + dblk * 8);
    uint4 vv = *(const uint4*)(v + r * 64 + dblk * 8);
    const unsigned short* pv = (const unsigned short*)&vv;
#pragma unroll
    for (int j = 0; j < 8; ++j)
      VT[(dblk * 8 + j) * 72 + r] = pv[j];
  }
  __syncthreads();
  const int lane = tid & 63, wid = tid >> 6;
  const int quad = lane >> 4, l15 = lane & 15;
  const int qs = wid << 4;
  short8 aq0 = *(const short8*)(&Qs[(qs + l15) * 72 + quad * 8]);
  short8 aq1 = *(const short8*)(&Qs[(qs + l15) * 72 + 32 + quad * 8]);
  floatx4 s[4] = {};
#pragma unroll
  for (int ni = 0; ni < 4; ++ni) {
    short8 b0 = *(const short8*)(&Ks[(ni * 16 + l15) * 72 + quad * 8]);
    short8 b1 = *(const short8*)(&Ks[(ni * 16 + l15) * 72 + 32 + quad * 8]);
    s[ni] = MFMA16(aq0, b0, s[ni]);
    s[ni] = MFMA16(aq1, b1, s[ni]);
  }
#pragma unroll
  for (int r = 0; r < 4; ++r) {
    float e0 = s[0][r] * 0.125f, e1 = s[1][r] * 0.125f;
    float e2 = s[2][r] * 0.125f, e3 = s[3][r] * 0.125f;
    float m = fmaxf(fmaxf(e0, e1), fmaxf(e2, e3));
    m = fmaxf(m, __shfl_xor(m, 1));
    m = fmaxf(m, __shfl_xor(m, 2));
    m = fmaxf(m, __shfl_xor(m, 4));
    m = fmaxf(m, __shfl_xor(m, 8));
    float x0 = __expf(e0 - m), x1 = __expf(e1 - m);
    float x2 = __expf(e2 - m), x3 = __expf(e3 - m);
    float t = x0 + x1 + x2 + x3;
    t += __shfl_xor(t, 1); t += __shfl_xor(t, 2);
    t += __shfl_xor(t, 4); t += __shfl_xor(t, 8);
    float inv = __builtin_amdgcn_rcpf(t);
    int row = qs + (quad << 2) + r;
    Ps[row * 72 +      l15] = f2bf(x0 * inv);
    Ps[row * 72 + 16 + l15] = f2bf(x1 * inv);
    Ps[row * 72 + 32 + l15] = f2bf(x2 * inv);
    Ps[row * 72 + 48 + l15] = f2bf(x3 * inv);
  }
  __syncthreads();
  short8 ap0 = *(const short8*)(&Ps[(qs + l15) * 72 + quad * 8]);
  short8 ap1 = *(const short8*)(&Ps[(qs + l15) * 72 + 32 + quad * 8]);
  floatx4 o[4] = {};
#pragma unroll
  for (int ni = 0; ni < 4; ++ni) {
    short8 b0 = *(const short8*)(&VT[(ni * 16 + l15) * 72 + quad * 8]);
    short8 b1 = *(const short8*)(&VT[(ni * 16 + l15) * 72 + 32 + quad * 8]);
    o[ni] = MFMA16(ap0, b0, o[ni]);
    o[ni] = MFMA16(ap1, b1, o[ni]);
  }
  unsigned short* outp = Ob + base;
#pragma unroll
  for (int ni = 0; ni < 4; ++ni)
#pragma unroll
    for (int r = 0; r < 4; ++r)
      outp[(qs + (quad << 2) + r) * 64 + ni * 16 + l15] = f2bf(o[ni][r]);
}

// ---------------- out gemm: Cp[ks][512][512] = Ob * Wo_f32 (partials) ------
// grid (512). Remap: xcd=id&7, j=id>>3: m=j&3, q=j>>2 (0..15): n=q&3,
// ks=xcd*4+(q>>2). The 4 m-blocks sharing a (n,ks) Wo chunk sit on one XCD.
// Plain fp32 stores to per-slice partial tiles; reduce_out sums them.
// Same v5 single-Bs + dbuf-As pipelined staging (16 steps).
__global__ __launch_bounds__(256, 3) void gemm_out(const unsigned short* __restrict__ A,
                                                   const float* __restrict__ Wo,
                                                   float* __restrict__ Cp) {
  __shared__ __align__(16) unsigned short As[2][128 * 64];
  __shared__ __align__(16) unsigned short Bs[128 * 64];
  const int tid = threadIdx.x;
  const int id = blockIdx.x;
  const int xcd = id & 7, bj = id >> 3;
  const int m0 = (bj & 3) << 7;
  const int q = bj >> 2;
  const int n0 = (q & 3) << 7;
  const int ks = (xcd << 2) | (q >> 2);
  const int kbase = ks << 10;
  const int lane = tid & 63, wid = tid >> 6;
  const int quad = lane >> 4, l15 = lane & 15;
  const int wm = wid >> 1, wn = wid & 1;
  const int n = tid & 127;
  const int octb = __builtin_amdgcn_readfirstlane(tid >> 7);
  const int nsteps = 16;

  float fB[32];
  floatx4 acc[4][4] = {};

  STAGE_TILE(A + (size_t)m0 * 32768 + kbase, 32768, As[0]);
  __builtin_amdgcn_sched_barrier(0);
  b_issue<512>(Wo + (size_t)kbase * 512 + n0, fB, n, octb);
  __builtin_amdgcn_sched_barrier(0);

  for (int t = 0; t < nsteps; ++t) {
    const int cur = t & 1;
    b_write(Bs, fB, n, octb);
    asm volatile("s_waitcnt vmcnt(0) lgkmcnt(0)" ::: "memory");
    __builtin_amdgcn_s_barrier();        // publish
    __builtin_amdgcn_sched_barrier(0);
    if (t + 1 < nsteps) {
      STAGE_TILE(A + (size_t)m0 * 32768 + kbase + ((t + 1) << 6), 32768, As[cur ^ 1]);
      __builtin_amdgcn_sched_barrier(0);
      b_issue<512>(Wo + (size_t)(kbase + ((t + 1) << 6)) * 512 + n0, fB, n, octb);
    }
    __builtin_amdgcn_sched_barrier(0);
#pragma unroll
    for (int kss = 0; kss < 2; ++kss) {
      short8 aF[4], bF[4];
#pragma unroll
      for (int mi = 0; mi < 4; ++mi) aF[mi] = FRAG(As[cur], wm * 64 + mi * 16 + l15, kss);
#pragma unroll
      for (int ni = 0; ni < 4; ++ni) bF[ni] = FRAG(Bs, wn * 64 + ni * 16 + l15, kss);
#pragma unroll
      for (int mi = 0; mi < 4; ++mi)
#pragma unroll
        for (int ni = 0; ni < 4; ++ni)
          acc[mi][ni] = MFMA16(aF[mi], bF[ni], acc[mi][ni]);
    }
    __builtin_amdgcn_s_barrier();        // Bs overwrite guard
  }
  float* outp = Cp + (size_t)ks * 262144;
#pragma unroll
  for (int ni = 0; ni < 4; ++ni) {
    int col = n0 + wn * 64 + ni * 16 + l15;
#pragma unroll
    for (int mi = 0; mi < 4; ++mi) {
      int row = m0 + wm * 64 + mi * 16 + (quad << 2);
#pragma unroll
      for (int r = 0; r < 4; ++r)
        outp[(size_t)(row + r) * 512 + col] = acc[mi][ni][r];
    }
  }
}

// ---------------- reduce 32 partial tiles + bias -> out --------------------
__global__ __launch_bounds__(256) void reduce_out(const float* __restrict__ Cp,
                                                  const float* __restrict__ bias,
                                                  float* __restrict__ C) {
  int idx = blockIdx.x * 256 + threadIdx.x;   // grid 1024 -> 262144 outputs
  float s = bias[idx & 511];
#pragma unroll
  for (int k = 0; k < 32; ++k) s += Cp[(size_t)k * 262144 + idx];
  C[idx] = s;
}

extern "C" void kernel_launch(void* const* d_in, const int* in_sizes, int n_in,
                              void* d_out, int out_size, void* d_ws, size_t ws_size,
                              hipStream_t stream) {
  const float* x  = (const float*)d_in[0];
  const float* z  = (const float*)d_in[1];
  const float* Wq = (const float*)d_in[2];
  const float* bq = (const float*)d_in[3];
  const float* Wk = (const float*)d_in[4];
  const float* bk = (const float*)d_in[5];
  const float* Wv = (const float*)d_in[6];
  const float* bv = (const float*)d_in[7];
  const float* Wo = (const float*)d_in[8];
  const float* bo = (const float*)d_in[9];
  float* out = (float*)d_out;
  char* ws = (char*)d_ws;

  unsigned short* Qb = (unsigned short*)(ws + 0);
  unsigned short* Kb = (unsigned short*)(ws + 33554432);
  unsigned short* Vb = (unsigned short*)(ws + 67108864);
  unsigned short* Ob = (unsigned short*)(ws + 100663296);
  unsigned short* xb = (unsigned short*)(ws + 134217728);
  unsigned short* zb = (unsigned short*)(ws + 134742016);
  float*          Cp = (float*)(ws + 135266304);            // 32MB partials

  convert_xz<<<dim3(192), 256, 0, stream>>>(x, z, xb, zb);

  gemm_qkv<<<dim3(1024, 1, 3), 256, 0, stream>>>(xb, zb, Wq, Wk, Wv,
                                                 bq, bk, bv, Qb, Kb, Vb);

  attn64<<<dim3(4096), 256, 0, stream>>>(Qb, Kb, Vb, Ob);

  gemm_out<<<dim3(512), 256, 0, stream>>>(Ob, Wo, Cp);

  reduce_out<<<dim3(1024), 256, 0, stream>>>(Cp, bo, out);
}